// Round 7
// baseline (77.946 us; speedup 1.0000x reference)
//
#include <hip/hip_runtime.h>

// Path signature depth-3, path (N=32, L=128, C=48) fp32 — fused single kernel.
//
// Math (R5/R9-validated, absmax 0.25):
//   v_t = p[t+1]-p[t], P_t[i] = p[t][i]-p[0][i],
//   G_t = P_t + v_t/2,  R_t = P_t/2 + v_t/6
//   S1 = p[127]-p[0];  S2[i,j] = sum_t G_t[i] v_t[j]   (register prefix a2)
//   S3[i,j,k] = sum_t (a2prefix + R_t[i] v_t[j]) v_t[k]
//   t-split x4 (32/32/32/31), Pi seeded globally per segment; exact fixup
//   S3 = sum_q [S3loc_q + a2pre_q (x) W_q], W_q = p[seg_end]-p[seg_start].
//
// R18 (R17 post-mortem): parallel tail regressed (+2.3us: 73.7KB LDS, 288+288
// slot traffic, 4x W-loads) -> reverted to R14's two-round tail (75.40 best).
// Occupancy axis closed (cap law 256/arg; s3 file=64 regs). Remaining 12.4us:
// VALU 5.2us/SIMD + LDS 5.4us/CU both ~58% utilized -> interleave loss at
// 2 waves/SIMD. This round, zero-pressure levers on the R14 base:
//  (1) s_setprio(1) around the per-iter FMA cluster — waves here are
//      independent post-staging (attn-like regime where T5 measured +4-7%),
//  (2) v_pk_fma_f32 op_sel-broadcast asm for the 32 s3 FMAs (kills {b,b}
//      splat movs if the compiler emits them; identical ops otherwise).
// Bit-identical arithmetic (absmax 0.25). Predicted kernel ~11.3-11.9us,
// total ~74.3-75.0. If <=0.4us gain -> structural ceiling, declare.

#define N_BATCH 32
#define LPATH   128
#define T_STEPS 127
#define C       48
#define C2      2304
#define C3      110592
#define OUT_PER_N (C + C2 + C3)      // 112944
#define PATH_PER_N (LPATH * C)       // 6144
#define GROUPS 27                    // 1728 (i,jg,kc) units / 64 lanes
#define RSLOT 36                     // per-q slots/round: 4jj*8k + 4 a2
#define LDS_FLOATS 6912              // max(v: 6096, reduce: 3*36*64=6912)

typedef float f32x2 __attribute__((ext_vector_type(2)));

// s3[p] += {t2.lo, t2.lo} * kk  (op_sel broadcasts src0's low half = b)
#define PK_S3(ACC, T2, KK)                                              \
    asm("v_pk_fma_f32 %0, %1, %2, %0 op_sel:[0,0,0] op_sel_hi:[0,1,1]"  \
        : "+v"(ACC) : "v"(T2), "v"(KK))

__global__ __launch_bounds__(256, 2) void sig_fused(const float* __restrict__ path,
                                                    float* __restrict__ out) {
    __shared__ float lds[LDS_FLOATS];

    int bid = blockIdx.x;
    int n = bid / GROUPS;
    int g = bid - n * GROUPS;
    int tid = threadIdx.x;
    int q = tid >> 6;                // t-segment 0..3
    int lane = tid & 63;

    const float* __restrict__ pb = path + n * PATH_PER_N;

    // unit U -> (i, jg, kc): U = i*36 + jg*6 + kc ; j = jg*8+[0,8), k = kc*8+[0,8)
    int U = g * 64 + lane;
    int i = U / 36;
    int rr = U - i * 36;
    int jg = rr / 6;
    int kc = rr - jg * 6;

    int T0 = q * 32;

    // ---- k-stream prologue: rows T0..T0+3 issued FIRST (latency hidden
    //      under the staging phase + barrier) ----
    const float* gk = pb + T0 * C + kc * 8;
    float4 A0 = *(const float4*)(gk + 0 * C);
    float4 A1 = *(const float4*)(gk + 0 * C + 4);
    float4 B0 = *(const float4*)(gk + 1 * C);
    float4 B1 = *(const float4*)(gk + 1 * C + 4);
    float4 C0 = *(const float4*)(gk + 2 * C);
    float4 C1 = *(const float4*)(gk + 2 * C + 4);
    float4 D0 = *(const float4*)(gk + 3 * C);
    float4 D1 = *(const float4*)(gk + 3 * C + 4);
    gk += 4 * C;                     // now points at row T0+4

    // ---- stage v = diff(p) into LDS (coalesced float4) ----
    {
        const float4* p4 = (const float4*)pb;
        float4* v4 = (float4*)lds;
        #pragma unroll
        for (int c = 0; c < 6; ++c) {
            int idx = tid + 256 * c;
            if (idx < (T_STEPS * C) / 4) {            // 1524
                float4 a = p4[idx];
                float4 b = p4[idx + C / 4];
                v4[idx] = make_float4(b.x - a.x, b.y - a.y, b.z - a.z, b.w - a.w);
            }
        }
    }
    // S1 (once per batch), overlapped with staging
    if (g == 0 && tid < C)
        out[(long)n * OUT_PER_N + tid] = pb[(LPATH - 1) * C + tid] - pb[tid];
    __syncthreads();

    float Pi = pb[T0 * C + i] - pb[i];   // exact global prefix at segment start
    float a2[8];
    f32x2 s3[8][4];                      // packed k-pairs: [jj][kpair]
    #pragma unroll
    for (int jj = 0; jj < 8; ++jj) {
        a2[jj] = 0.f;
        #pragma unroll
        for (int p = 0; p < 4; ++p) s3[jj][p] = (f32x2){0.f, 0.f};
    }

    // ---- main loop: j/i from LDS (imm offsets), k from global (period-4
    //      slots, distance-3 prefetch, zero rotation movs) ----
    const float* ldsJ = lds + T0 * C + jg * 8;
    const float* ldsI = lds + T0 * C + i;

    // step: v_t from (N - O) rows; LDS v row at REL; then load row into O.
#define KSTEP(O0, O1, N0, N1, REL, DOLOAD) do {                         \
        float  vi_ = ldsI[(REL) * C];                                   \
        float4 vj0 = *(const float4*)(ldsJ + (REL) * C);                \
        float4 vj1 = *(const float4*)(ldsJ + (REL) * C + 4);            \
        f32x2 kk0 = {N0.x - O0.x, N0.y - O0.y};                         \
        f32x2 kk1 = {N0.z - O0.z, N0.w - O0.w};                         \
        f32x2 kk2 = {N1.x - O1.x, N1.y - O1.y};                         \
        f32x2 kk3 = {N1.z - O1.z, N1.w - O1.w};                         \
        if (DOLOAD) {                                                   \
            O0 = *(const float4*)(gk + (REL) * C);                      \
            O1 = *(const float4*)(gk + (REL) * C + 4);                  \
        }                                                               \
        float G = Pi + 0.5f * vi_;                                      \
        float R = 0.5f * Pi + (1.0f / 6.0f) * vi_;                      \
        Pi += vi_;                                                      \
        f32x2 RG = {R, G};                                              \
        float vja[8] = {vj0.x, vj0.y, vj0.z, vj0.w,                     \
                        vj1.x, vj1.y, vj1.z, vj1.w};                    \
        __builtin_amdgcn_s_setprio(1);                                  \
        _Pragma("unroll")                                               \
        for (int jj = 0; jj < 8; ++jj) {                                \
            f32x2 vjp = {vja[jj], vja[jj]};                             \
            f32x2 aap = {a2[jj], a2[jj]};                               \
            f32x2 t2v = __builtin_elementwise_fma(RG, vjp, aap);        \
            a2[jj] = t2v.y;                                             \
            PK_S3(s3[jj][0], t2v, kk0);                                 \
            PK_S3(s3[jj][1], t2v, kk1);                                 \
            PK_S3(s3[jj][2], t2v, kk2);                                 \
            PK_S3(s3[jj][3], t2v, kk3);                                 \
        }                                                               \
        __builtin_amdgcn_s_setprio(0);                                  \
    } while (0)

    // q<3: 8 blocks of 4 (loads in last block harmlessly over-prefetch rows
    // <= T0+35 <= 99). q==3: 7 blocks (max loaded row = 127) + 3-iter tail
    // with no loads (slots already hold rows 124..127). Never reads past
    // row 127 -> no OOB, no clamp.
    int NB = (q == 3) ? 7 : 8;
    #pragma unroll 1
    for (int b = 0; b < NB; ++b) {
        KSTEP(A0, A1, B0, B1, 0, 1);
        KSTEP(B0, B1, C0, C1, 1, 1);
        KSTEP(C0, C1, D0, D1, 2, 1);
        KSTEP(D0, D1, A0, A1, 3, 1);
        ldsJ += 4 * C; ldsI += 4 * C; gk += 4 * C;
    }
    if (q == 3) {                    // t = 124, 125, 126
        KSTEP(A0, A1, B0, B1, 0, 0);
        KSTEP(B0, B1, C0, C1, 1, 0);
        KSTEP(C0, C1, D0, D1, 2, 0);
    }
#undef KSTEP

    // ---- W vectors for the fixup (wave 3 only; L1/L2-hot global reads) ----
    float4 W10, W11, W20, W21, W30, W31;
    if (q == 3) {
        float4 p32a = *(const float4*)(pb + 32 * C + kc * 8);
        float4 p32b = *(const float4*)(pb + 32 * C + kc * 8 + 4);
        float4 p64a = *(const float4*)(pb + 64 * C + kc * 8);
        float4 p64b = *(const float4*)(pb + 64 * C + kc * 8 + 4);
        float4 p96a = *(const float4*)(pb + 96 * C + kc * 8);
        float4 p96b = *(const float4*)(pb + 96 * C + kc * 8 + 4);
        float4 pEa  = *(const float4*)(pb + 127 * C + kc * 8);
        float4 pEb  = *(const float4*)(pb + 127 * C + kc * 8 + 4);
        W10 = make_float4(p64a.x - p32a.x, p64a.y - p32a.y, p64a.z - p32a.z, p64a.w - p32a.w);
        W11 = make_float4(p64b.x - p32b.x, p64b.y - p32b.y, p64b.z - p32b.z, p64b.w - p32b.w);
        W20 = make_float4(p96a.x - p64a.x, p96a.y - p64a.y, p96a.z - p64a.z, p96a.w - p64a.w);
        W21 = make_float4(p96b.x - p64b.x, p96b.y - p64b.y, p96b.z - p64b.z, p96b.w - p64b.w);
        W30 = make_float4(pEa.x - p96a.x, pEa.y - p96a.y, pEa.z - p96a.z, pEa.w - p96a.w);
        W31 = make_float4(pEb.x - p96b.x, pEb.y - p96b.y, pEb.z - p96b.z, pEb.w - p96b.w);
    }

    __syncthreads();                 // all waves done reading v

    // ---- 2 rounds: waves 0-2 deposit 4 jj's, wave 3 combines + stores ----
    long obase = (long)n * OUT_PER_N + C;
    #pragma unroll
    for (int r = 0; r < 2; ++r) {
        if (r) __syncthreads();      // protect previous round's reads
        if (q < 3) {
            float* dst = lds + (q * RSLOT) * 64 + lane;   // lane-major slots
            #pragma unroll
            for (int jjr = 0; jjr < 4; ++jjr) {
                int jj = r * 4 + jjr;
                dst[(jjr * 8 + 0) * 64] = s3[jj][0][0];
                dst[(jjr * 8 + 1) * 64] = s3[jj][0][1];
                dst[(jjr * 8 + 2) * 64] = s3[jj][1][0];
                dst[(jjr * 8 + 3) * 64] = s3[jj][1][1];
                dst[(jjr * 8 + 4) * 64] = s3[jj][2][0];
                dst[(jjr * 8 + 5) * 64] = s3[jj][2][1];
                dst[(jjr * 8 + 6) * 64] = s3[jj][3][0];
                dst[(jjr * 8 + 7) * 64] = s3[jj][3][1];
                dst[(32 + jjr) * 64]    = a2[jj];
            }
        }
        __syncthreads();
        if (q == 3) {
            #pragma unroll
            for (int jjr = 0; jjr < 4; ++jjr) {
                int jj = r * 4 + jjr;
                const float* s0 = lds + (0 * RSLOT) * 64 + lane;
                const float* s1 = lds + (1 * RSLOT) * 64 + lane;
                const float* s2 = lds + (2 * RSLOT) * 64 + lane;
                float a2q0 = s0[(32 + jjr) * 64];
                float a2q1 = s1[(32 + jjr) * 64];
                float a2q2 = s2[(32 + jjr) * 64];
                float pre1 = a2q0;
                float pre2 = a2q0 + a2q1;
                float pre3 = pre2 + a2q2;
                float acc[8];
                #pragma unroll
                for (int c = 0; c < 8; ++c) {
                    int sl = (jjr * 8 + c) * 64;
                    acc[c] = s0[sl] + s1[sl] + s2[sl];
                }
                acc[0] += s3[jj][0][0] + pre1 * W10.x + pre2 * W20.x + pre3 * W30.x;
                acc[1] += s3[jj][0][1] + pre1 * W10.y + pre2 * W20.y + pre3 * W30.y;
                acc[2] += s3[jj][1][0] + pre1 * W10.z + pre2 * W20.z + pre3 * W30.z;
                acc[3] += s3[jj][1][1] + pre1 * W10.w + pre2 * W20.w + pre3 * W30.w;
                acc[4] += s3[jj][2][0] + pre1 * W11.x + pre2 * W21.x + pre3 * W31.x;
                acc[5] += s3[jj][2][1] + pre1 * W11.y + pre2 * W21.y + pre3 * W31.y;
                acc[6] += s3[jj][3][0] + pre1 * W11.z + pre2 * W21.z + pre3 * W31.z;
                acc[7] += s3[jj][3][1] + pre1 * W11.w + pre2 * W21.w + pre3 * W31.w;

                float* dst = out + obase + C2 + (long)(i * C + jg * 8 + jj) * C + kc * 8;
                *(float4*)(dst)     = make_float4(acc[0], acc[1], acc[2], acc[3]);
                *(float4*)(dst + 4) = make_float4(acc[4], acc[5], acc[6], acc[7]);
                if (kc == 0)
                    out[obase + i * C + jg * 8 + jj] = pre3 + a2[jj];   // S2
            }
        }
    }
}

extern "C" void kernel_launch(void* const* d_in, const int* in_sizes, int n_in,
                              void* d_out, int out_size, void* d_ws, size_t ws_size,
                              hipStream_t stream) {
    const float* path = (const float*)d_in[0];
    float* out = (float*)d_out;
    (void)d_ws; (void)ws_size;

    sig_fused<<<N_BATCH * GROUPS, 256, 0, stream>>>(path, out);
}

// Round 8
// 76.788 us; speedup vs baseline: 1.0151x; 1.0151x over previous
//
#include <hip/hip_runtime.h>

// Path signature depth-3, path (N=32, L=128, C=48) fp32 — fused single kernel.
//
// Math (R5/R9-validated, absmax 0.25):
//   v_t = p[t+1]-p[t], P_t[i] = p[t][i]-p[0][i],
//   G_t = P_t + v_t/2,  R_t = P_t/2 + v_t/6
//   S1 = p[127]-p[0];  S2[i,j] = sum_t G_t[i] v_t[j]   (register prefix a2)
//   S3[i,j,k] = sum_t (a2prefix + R_t[i] v_t[j]) v_t[k]
//   t-split x4 (32/32/32/31), Pi seeded globally per segment; exact fixup
//   S3 = sum_q [S3loc_q + a2pre_q (x) W_q], W_q = p[seg_end]-p[seg_start].
//
// R19 — FINAL REVERT to R14 (best measured, 75.40us). Eight-round ledger:
// R12 (+3.2: rotation movs), R13 (+6.2: depth-1 latency trap), R15/R16
// (spill: cap law VGPR=256/arg, s3 file=64 regs walls occupancy at 2
// waves/SIMD), R17 (+2.3: parallel tail traffic), R18 (+2.5: asm fences
// scheduler, setprio null in lockstep loops). Kernel ~12.4us = ~58% of
// fp32 vector peak; remaining headroom needs >=3 waves/SIMD (register-
// walled) — every substitute measured negative. 84% of dur_us is fixed
// harness fill at 82% HBM peak. R14 body verbatim below.

#define N_BATCH 32
#define LPATH   128
#define T_STEPS 127
#define C       48
#define C2      2304
#define C3      110592
#define OUT_PER_N (C + C2 + C3)      // 112944
#define PATH_PER_N (LPATH * C)       // 6144
#define GROUPS 27                    // 1728 (i,jg,kc) units / 64 lanes
#define RSLOT 36                     // per-q slots/round: 4jj*8k + 4 a2
#define LDS_FLOATS 6912              // max(v: 6096, reduce: 3*36*64=6912)

typedef float f32x2 __attribute__((ext_vector_type(2)));

__global__ __launch_bounds__(256, 2) void sig_fused(const float* __restrict__ path,
                                                    float* __restrict__ out) {
    __shared__ float lds[LDS_FLOATS];

    int bid = blockIdx.x;
    int n = bid / GROUPS;
    int g = bid - n * GROUPS;
    int tid = threadIdx.x;
    int q = tid >> 6;                // t-segment 0..3
    int lane = tid & 63;

    const float* __restrict__ pb = path + n * PATH_PER_N;

    // unit U -> (i, jg, kc): U = i*36 + jg*6 + kc ; j = jg*8+[0,8), k = kc*8+[0,8)
    int U = g * 64 + lane;
    int i = U / 36;
    int rr = U - i * 36;
    int jg = rr / 6;
    int kc = rr - jg * 6;

    int T0 = q * 32;

    // ---- k-stream prologue: rows T0..T0+3 issued FIRST (latency hidden
    //      under the staging phase + barrier) ----
    const float* gk = pb + T0 * C + kc * 8;
    float4 A0 = *(const float4*)(gk + 0 * C);
    float4 A1 = *(const float4*)(gk + 0 * C + 4);
    float4 B0 = *(const float4*)(gk + 1 * C);
    float4 B1 = *(const float4*)(gk + 1 * C + 4);
    float4 C0 = *(const float4*)(gk + 2 * C);
    float4 C1 = *(const float4*)(gk + 2 * C + 4);
    float4 D0 = *(const float4*)(gk + 3 * C);
    float4 D1 = *(const float4*)(gk + 3 * C + 4);
    gk += 4 * C;                     // now points at row T0+4

    // ---- stage v = diff(p) into LDS (coalesced float4) ----
    {
        const float4* p4 = (const float4*)pb;
        float4* v4 = (float4*)lds;
        #pragma unroll
        for (int c = 0; c < 6; ++c) {
            int idx = tid + 256 * c;
            if (idx < (T_STEPS * C) / 4) {            // 1524
                float4 a = p4[idx];
                float4 b = p4[idx + C / 4];
                v4[idx] = make_float4(b.x - a.x, b.y - a.y, b.z - a.z, b.w - a.w);
            }
        }
    }
    // S1 (once per batch), overlapped with staging
    if (g == 0 && tid < C)
        out[(long)n * OUT_PER_N + tid] = pb[(LPATH - 1) * C + tid] - pb[tid];
    __syncthreads();

    float Pi = pb[T0 * C + i] - pb[i];   // exact global prefix at segment start
    float a2[8];
    f32x2 s3[8][4];                      // packed k-pairs: [jj][kpair]
    #pragma unroll
    for (int jj = 0; jj < 8; ++jj) {
        a2[jj] = 0.f;
        #pragma unroll
        for (int p = 0; p < 4; ++p) s3[jj][p] = (f32x2){0.f, 0.f};
    }

    // ---- main loop: j/i from LDS (imm offsets), k from global (period-4
    //      slots, distance-3 prefetch, zero rotation movs) ----
    const float* ldsJ = lds + T0 * C + jg * 8;
    const float* ldsI = lds + T0 * C + i;

    // step: v_t from (N - O) rows; LDS v row at REL; then load row into O.
#define KSTEP(O0, O1, N0, N1, REL, DOLOAD) do {                         \
        float  vi_ = ldsI[(REL) * C];                                   \
        float4 vj0 = *(const float4*)(ldsJ + (REL) * C);                \
        float4 vj1 = *(const float4*)(ldsJ + (REL) * C + 4);            \
        f32x2 kk0 = {N0.x - O0.x, N0.y - O0.y};                         \
        f32x2 kk1 = {N0.z - O0.z, N0.w - O0.w};                         \
        f32x2 kk2 = {N1.x - O1.x, N1.y - O1.y};                         \
        f32x2 kk3 = {N1.z - O1.z, N1.w - O1.w};                         \
        if (DOLOAD) {                                                   \
            O0 = *(const float4*)(gk + (REL) * C);                      \
            O1 = *(const float4*)(gk + (REL) * C + 4);                  \
        }                                                               \
        float G = Pi + 0.5f * vi_;                                      \
        float R = 0.5f * Pi + (1.0f / 6.0f) * vi_;                      \
        Pi += vi_;                                                      \
        f32x2 RG = {R, G};                                              \
        float vja[8] = {vj0.x, vj0.y, vj0.z, vj0.w,                     \
                        vj1.x, vj1.y, vj1.z, vj1.w};                    \
        _Pragma("unroll")                                               \
        for (int jj = 0; jj < 8; ++jj) {                                \
            f32x2 vjp = {vja[jj], vja[jj]};                             \
            f32x2 aap = {a2[jj], a2[jj]};                               \
            f32x2 t2v = __builtin_elementwise_fma(RG, vjp, aap);        \
            a2[jj] = t2v.y;                                             \
            f32x2 bb = {t2v.x, t2v.x};                                  \
            s3[jj][0] = __builtin_elementwise_fma(bb, kk0, s3[jj][0]);  \
            s3[jj][1] = __builtin_elementwise_fma(bb, kk1, s3[jj][1]);  \
            s3[jj][2] = __builtin_elementwise_fma(bb, kk2, s3[jj][2]);  \
            s3[jj][3] = __builtin_elementwise_fma(bb, kk3, s3[jj][3]);  \
        }                                                               \
    } while (0)

    // q<3: 8 blocks of 4 (loads in last block harmlessly over-prefetch rows
    // <= T0+35 <= 99). q==3: 7 blocks (max loaded row = 127) + 3-iter tail
    // with no loads (slots already hold rows 124..127). Never reads past
    // row 127 -> no OOB, no clamp.
    int NB = (q == 3) ? 7 : 8;
    for (int b = 0; b < NB; ++b) {
        KSTEP(A0, A1, B0, B1, 0, 1);
        KSTEP(B0, B1, C0, C1, 1, 1);
        KSTEP(C0, C1, D0, D1, 2, 1);
        KSTEP(D0, D1, A0, A1, 3, 1);
        ldsJ += 4 * C; ldsI += 4 * C; gk += 4 * C;
    }
    if (q == 3) {                    // t = 124, 125, 126
        KSTEP(A0, A1, B0, B1, 0, 0);
        KSTEP(B0, B1, C0, C1, 1, 0);
        KSTEP(C0, C1, D0, D1, 2, 0);
    }
#undef KSTEP

    // ---- W vectors for the fixup (wave 3 only; L1/L2-hot global reads) ----
    float4 W10, W11, W20, W21, W30, W31;
    if (q == 3) {
        float4 p32a = *(const float4*)(pb + 32 * C + kc * 8);
        float4 p32b = *(const float4*)(pb + 32 * C + kc * 8 + 4);
        float4 p64a = *(const float4*)(pb + 64 * C + kc * 8);
        float4 p64b = *(const float4*)(pb + 64 * C + kc * 8 + 4);
        float4 p96a = *(const float4*)(pb + 96 * C + kc * 8);
        float4 p96b = *(const float4*)(pb + 96 * C + kc * 8 + 4);
        float4 pEa  = *(const float4*)(pb + 127 * C + kc * 8);
        float4 pEb  = *(const float4*)(pb + 127 * C + kc * 8 + 4);
        W10 = make_float4(p64a.x - p32a.x, p64a.y - p32a.y, p64a.z - p32a.z, p64a.w - p32a.w);
        W11 = make_float4(p64b.x - p32b.x, p64b.y - p32b.y, p64b.z - p32b.z, p64b.w - p32b.w);
        W20 = make_float4(p96a.x - p64a.x, p96a.y - p64a.y, p96a.z - p64a.z, p96a.w - p64a.w);
        W21 = make_float4(p96b.x - p64b.x, p96b.y - p64b.y, p96b.z - p64b.z, p96b.w - p64b.w);
        W30 = make_float4(pEa.x - p96a.x, pEa.y - p96a.y, pEa.z - p96a.z, pEa.w - p96a.w);
        W31 = make_float4(pEb.x - p96b.x, pEb.y - p96b.y, pEb.z - p96b.z, pEb.w - p96b.w);
    }

    __syncthreads();                 // all waves done reading v

    // ---- 2 rounds: waves 0-2 deposit 4 jj's, wave 3 combines + stores ----
    long obase = (long)n * OUT_PER_N + C;
    #pragma unroll
    for (int r = 0; r < 2; ++r) {
        if (r) __syncthreads();      // protect previous round's reads
        if (q < 3) {
            float* dst = lds + (q * RSLOT) * 64 + lane;   // lane-major slots
            #pragma unroll
            for (int jjr = 0; jjr < 4; ++jjr) {
                int jj = r * 4 + jjr;
                dst[(jjr * 8 + 0) * 64] = s3[jj][0][0];
                dst[(jjr * 8 + 1) * 64] = s3[jj][0][1];
                dst[(jjr * 8 + 2) * 64] = s3[jj][1][0];
                dst[(jjr * 8 + 3) * 64] = s3[jj][1][1];
                dst[(jjr * 8 + 4) * 64] = s3[jj][2][0];
                dst[(jjr * 8 + 5) * 64] = s3[jj][2][1];
                dst[(jjr * 8 + 6) * 64] = s3[jj][3][0];
                dst[(jjr * 8 + 7) * 64] = s3[jj][3][1];
                dst[(32 + jjr) * 64]    = a2[jj];
            }
        }
        __syncthreads();
        if (q == 3) {
            #pragma unroll
            for (int jjr = 0; jjr < 4; ++jjr) {
                int jj = r * 4 + jjr;
                const float* s0 = lds + (0 * RSLOT) * 64 + lane;
                const float* s1 = lds + (1 * RSLOT) * 64 + lane;
                const float* s2 = lds + (2 * RSLOT) * 64 + lane;
                float a2q0 = s0[(32 + jjr) * 64];
                float a2q1 = s1[(32 + jjr) * 64];
                float a2q2 = s2[(32 + jjr) * 64];
                float pre1 = a2q0;
                float pre2 = a2q0 + a2q1;
                float pre3 = pre2 + a2q2;
                float acc[8];
                #pragma unroll
                for (int c = 0; c < 8; ++c) {
                    int sl = (jjr * 8 + c) * 64;
                    acc[c] = s0[sl] + s1[sl] + s2[sl];
                }
                acc[0] += s3[jj][0][0] + pre1 * W10.x + pre2 * W20.x + pre3 * W30.x;
                acc[1] += s3[jj][0][1] + pre1 * W10.y + pre2 * W20.y + pre3 * W30.y;
                acc[2] += s3[jj][1][0] + pre1 * W10.z + pre2 * W20.z + pre3 * W30.z;
                acc[3] += s3[jj][1][1] + pre1 * W10.w + pre2 * W20.w + pre3 * W30.w;
                acc[4] += s3[jj][2][0] + pre1 * W11.x + pre2 * W21.x + pre3 * W31.x;
                acc[5] += s3[jj][2][1] + pre1 * W11.y + pre2 * W21.y + pre3 * W31.y;
                acc[6] += s3[jj][3][0] + pre1 * W11.z + pre2 * W21.z + pre3 * W31.z;
                acc[7] += s3[jj][3][1] + pre1 * W11.w + pre2 * W21.w + pre3 * W31.w;

                float* dst = out + obase + C2 + (long)(i * C + jg * 8 + jj) * C + kc * 8;
                *(float4*)(dst)     = make_float4(acc[0], acc[1], acc[2], acc[3]);
                *(float4*)(dst + 4) = make_float4(acc[4], acc[5], acc[6], acc[7]);
                if (kc == 0)
                    out[obase + i * C + jg * 8 + jj] = pre3 + a2[jj];   // S2
            }
        }
    }
}

extern "C" void kernel_launch(void* const* d_in, const int* in_sizes, int n_in,
                              void* d_out, int out_size, void* d_ws, size_t ws_size,
                              hipStream_t stream) {
    const float* path = (const float*)d_in[0];
    float* out = (float*)d_out;
    (void)d_ws; (void)ws_size;

    sig_fused<<<N_BATCH * GROUPS, 256, 0, stream>>>(path, out);
}